// Round 1
// baseline (171.262 us; speedup 1.0000x reference)
//
#include <hip/hip_runtime.h>

// AliasFreeActivation fused kernel (gfx950)
// x: (2,256,84,84) f32 -> up x4 (24-tap separable) -> lrelu(0.2) ->
// down x2 (12-tap separable) -> crop 10 -> out (2,256,148,148) f32
//
// Per-tile fusion: each block computes a 32x32 output tile for one plane.
// All intermediates live in LDS; no workspace needed.

constexpr int IN_HW  = 84;
constexpr int OUT_HW = 148;
constexpr int Z      = 336;   // intermediate (4x upsampled) resolution
constexpr int KU     = 24;    // up filter taps
constexpr int KD     = 12;    // down filter taps
constexpr int TILE   = 32;    // output tile edge
constexpr int ZT     = 2 * TILE + 10;  // 74: z rows/cols needed per tile
constexpr int NU     = 26;    // staged input/up-h rows (and input cols)
constexpr float SLOPE = 0.2f;

__global__ __launch_bounds__(256) void afa_fused(
    const float* __restrict__ x,
    const float* __restrict__ ku,
    const float* __restrict__ kd,
    float* __restrict__ out)
{
    __shared__ float s_ku[KU];
    __shared__ float s_kd[KD];
    __shared__ float s_in[NU][NU];     // input patch
    __shared__ float s_uph[NU][ZT];    // horizontal-up result (rows = input rows)
    __shared__ float s_z[ZT][ZT];      // lrelu(upsampled) patch
    __shared__ float s_t3[ZT][TILE];   // horizontal-down result

    const int tid = threadIdx.x;
    const int tx  = blockIdx.x;        // tile col
    const int ty  = blockIdx.y;        // tile row
    const int pz  = blockIdx.z;        // plane = b*C + c

    const int ox0 = tx * TILE;
    const int oy0 = ty * TILE;
    const int rz0 = 2 * oy0 + 15;      // first z row needed
    const int cu0 = 2 * ox0 + 15;      // first z col needed
    const int iu0 = (2 * oy0 + 25) / 4 - 5;  // first staged input row
    const int ic0 = (2 * ox0 + 25) / 4 - 5;  // first staged input col

    if (tid < KU) s_ku[tid] = ku[tid];
    if (tid < KD) s_kd[tid] = kd[tid];

    // ---- phase 0: stage input patch (zero-fill OOB) ----
    const float* xin = x + (size_t)pz * IN_HW * IN_HW;
    for (int e = tid; e < NU * NU; e += 256) {
        int r = e / NU, c = e % NU;
        int gr = iu0 + r, gc = ic0 + c;
        float v = 0.0f;
        if (gr >= 0 && gr < IN_HW && gc >= 0 && gc < IN_HW)
            v = xin[gr * IN_HW + gc];
        s_in[r][c] = v;
    }
    __syncthreads();

    // ---- phase 1: horizontal up-conv (polyphase, 6 taps) ----
    // uph[r][cu] = sum_t ku[ph+4t] * x[r][q - t],  ph=(cu+2)&3, q=floor((cu+10)/4)
    for (int e = tid; e < NU * ZT; e += 256) {
        int r = e / ZT, lc = e % ZT;
        int cu = cu0 + lc;
        int ph = (cu + 2) & 3;
        int lq = ((cu + 10 - ph) >> 2) - ic0;  // local input col of tap t=0; in [5,24]
        float acc = 0.0f;
#pragma unroll
        for (int t = 0; t < 6; ++t)
            acc += s_ku[ph + 4 * t] * s_in[r][lq - t];
        s_uph[r][lc] = acc;
    }
    __syncthreads();

    // ---- phase 2: vertical up-conv + leaky relu -> z ----
    for (int e = tid; e < ZT * ZT; e += 256) {
        int lr = e / ZT, lc = e % ZT;
        int rz = rz0 + lr;
        int cu = cu0 + lc;
        float v = 0.0f;
        if (rz < Z && cu < Z) {   // rz0,cu0 >= 15 so never negative
            int ph = (rz + 2) & 3;
            int lq = ((rz + 10 - ph) >> 2) - iu0;  // local up-h row of tap t=0
            float acc = 0.0f;
#pragma unroll
            for (int t = 0; t < 6; ++t)
                acc += s_ku[ph + 4 * t] * s_uph[lq - t][lc];
            v = (acc > 0.0f) ? acc : SLOPE * acc;
        }
        s_z[lr][lc] = v;
    }
    __syncthreads();

    // ---- phase 3: horizontal down-conv -> t3 (cols j+10, j in tile) ----
    // t3[r][j+10] = sum_s kd[s] * z[r][2(j+10)+6-s]; local z col = 2*lx+11-s
    for (int e = tid; e < ZT * TILE; e += 256) {
        int lr = e / TILE, lx = e % TILE;
        float acc = 0.0f;
#pragma unroll
        for (int s = 0; s < 12; ++s)
            acc += s_kd[s] * s_z[lr][2 * lx + 11 - s];
        s_t3[lr][lx] = acc;
    }
    __syncthreads();

    // ---- phase 4: vertical down-conv + crop -> out ----
    // out[i][j] = sum_s kd[s] * t3[2i+26-s][j+10]; local t3 row = 2*li+11-s
    float* o = out + (size_t)pz * OUT_HW * OUT_HW;
    for (int e = tid; e < TILE * TILE; e += 256) {
        int li = e / TILE, lx = e % TILE;
        int i = oy0 + li, j = ox0 + lx;
        if (i < OUT_HW && j < OUT_HW) {
            float acc = 0.0f;
#pragma unroll
            for (int s = 0; s < 12; ++s)
                acc += s_kd[s] * s_t3[2 * li + 11 - s][lx];
            o[(size_t)i * OUT_HW + j] = acc;
        }
    }
}

extern "C" void kernel_launch(void* const* d_in, const int* in_sizes, int n_in,
                              void* d_out, int out_size, void* d_ws, size_t ws_size,
                              hipStream_t stream) {
    const float* x  = (const float*)d_in[0];
    const float* ku = (const float*)d_in[1];
    const float* kd = (const float*)d_in[2];
    float* out = (float*)d_out;

    const int planes = 2 * 256;                 // B*C
    const int tiles = (OUT_HW + TILE - 1) / TILE;  // 5
    dim3 grid(tiles, tiles, planes);
    afa_fused<<<grid, dim3(256), 0, stream>>>(x, ku, kd, out);
}

// Round 2
// 69.056 us; speedup vs baseline: 2.4800x; 2.4800x over previous
//
#include <hip/hip_runtime.h>

// AliasFreeActivation fused kernel (gfx950), round 2: register-blocked.
// x: (2,256,84,84) f32 -> up x4 (24-tap separable) -> lrelu(0.2) ->
// down x2 (12-tap separable) -> crop 10 -> out (2,256,148,148) f32
//
// Each block: one 32x32 output tile of one plane. Polyphase structure is
// compile-time static because tile origins are multiples of 32:
//   up-h:  cu0 = 2*ox0+15, base = cu0+10+4g ≡ 1 (mod 4) -> phases (1,2,3,0)
//   up-v:  rz0 = 2*oy0+15, same pattern
//   window start for a 4-output group g is simply col/row 5+g - 5 = g.
// Filters live in SGPRs via readfirstlane; all inner indices static.

constexpr int IN_HW  = 84;
constexpr int OUT_HW = 148;
constexpr int Z      = 336;
constexpr int TILE   = 32;
constexpr int ZT     = 74;   // z rows/cols needed per tile
constexpr int ZTP    = 76;   // padded col stride (16B-aligned groups)
constexpr int NU     = 26;   // staged input rows/cols
constexpr int NUP    = 28;   // padded input col stride
constexpr int T3P    = 36;   // t3 col stride (break 128B-stride conflicts)
constexpr float SLOPE = 0.2f;

__device__ __forceinline__ float rfl(float v) {
    return __uint_as_float(__builtin_amdgcn_readfirstlane(__float_as_uint(v)));
}
__device__ __forceinline__ float lrelu(float v) {
    return v > 0.0f ? v : SLOPE * v;
}
__device__ __forceinline__ float f4c(const float4& v, int i) {
    return i == 0 ? v.x : i == 1 ? v.y : i == 2 ? v.z : v.w;
}
#define F4FMA(acc, c, W) { (acc).x += (c)*(W).x; (acc).y += (c)*(W).y; \
                           (acc).z += (c)*(W).z; (acc).w += (c)*(W).w; }

__global__ __launch_bounds__(256, 4) void afa_fused(
    const float* __restrict__ x,
    const float* __restrict__ ku,
    const float* __restrict__ kd,
    float* __restrict__ out)
{
    __shared__ __align__(16) float s_z[ZT][ZTP];                 // 22496 B
    __shared__ __align__(16) float s_buf[NU*NUP + NU*ZTP];       // 10816 B
    float (*s_in)[NUP]  = (float(*)[NUP]) s_buf;                 // [26][28]
    float (*s_uph)[ZTP] = (float(*)[ZTP])(s_buf + NU*NUP);       // [26][76]
    float (*s_t3)[T3P]  = (float(*)[T3P]) s_buf;                 // [74][36] (reuse)

    const int tid = threadIdx.x;
    const int tx = blockIdx.x, ty = blockIdx.y, pz = blockIdx.z;
    const int ox0 = tx * TILE, oy0 = ty * TILE;
    const int rz0 = 2 * oy0 + 15;
    const int cu0 = 2 * ox0 + 15;
    const int iu0 = 16 * ty + 1;   // first staged input row
    const int ic0 = 16 * tx + 1;   // first staged input col

    // Filters -> SGPRs (uniform values).
    float fu[24], fd[12];
#pragma unroll
    for (int i = 0; i < 24; ++i) fu[i] = rfl(ku[i]);
#pragma unroll
    for (int i = 0; i < 12; ++i) fd[i] = rfl(kd[i]);

    // ---- P0: stage input patch (zero-fill OOB) ----
    const float* xin = x + (size_t)pz * IN_HW * IN_HW;
    for (int e = tid; e < NU * NU; e += 256) {
        int r = e / NU, c = e - r * NU;
        int gr = iu0 + r, gc = ic0 + c;
        float v = 0.0f;
        if (gr >= 0 && gr < IN_HW && gc >= 0 && gc < IN_HW)
            v = xin[gr * IN_HW + gc];
        s_in[r][c] = v;
    }
    __syncthreads();

    // ---- P1: horizontal up-conv, 4 outputs/thread ----
    // group g covers cols 4g..4g+3; input window = s_in[r][g .. g+6]
    for (int e = tid; e < NU * 19; e += 256) {
        int r = e / 19, g = e - r * 19;
        float w[7];
#pragma unroll
        for (int t = 0; t < 7; ++t) w[t] = s_in[r][g + t];
        float4 a;
        a.x = fu[1]*w[5] + fu[5]*w[4] + fu[9]*w[3]  + fu[13]*w[2] + fu[17]*w[1] + fu[21]*w[0];
        a.y = fu[2]*w[5] + fu[6]*w[4] + fu[10]*w[3] + fu[14]*w[2] + fu[18]*w[1] + fu[22]*w[0];
        a.z = fu[3]*w[5] + fu[7]*w[4] + fu[11]*w[3] + fu[15]*w[2] + fu[19]*w[1] + fu[23]*w[0];
        a.w = fu[0]*w[6] + fu[4]*w[5] + fu[8]*w[4]  + fu[12]*w[3] + fu[16]*w[2] + fu[20]*w[1];
        *(float4*)&s_uph[r][4 * g] = a;
    }
    __syncthreads();

    // ---- P2: vertical up-conv + lrelu, 4 rows x 4 cols per thread ----
    // rowgroup rg covers z rows 4rg..4rg+3; window rows s_uph[rg .. rg+6]
    for (int e = tid; e < 19 * 19; e += 256) {
        int rg = e / 19, cg = e - rg * 19;
        float4 W[7];
#pragma unroll
        for (int t = 0; t < 7; ++t)
            W[t] = *(const float4*)&s_uph[rg + t][4 * cg];
        const int cc = cu0 + 4 * cg;
#pragma unroll
        for (int m = 0; m < 4; ++m) {
            const int ph = (m + 1) & 3;
            const int b  = (m == 3) ? 6 : 5;
            float4 a = {0.f, 0.f, 0.f, 0.f};
#pragma unroll
            for (int t = 0; t < 6; ++t) F4FMA(a, fu[ph + 4 * t], W[b - t]);
            int lr = 4 * rg + m;
            int rz = rz0 + lr;
            if (lr < ZT) {
                float4 v;
                bool rok = rz < Z;
                v.x = (rok && cc + 0 < Z) ? lrelu(a.x) : 0.0f;
                v.y = (rok && cc + 1 < Z) ? lrelu(a.y) : 0.0f;
                v.z = (rok && cc + 2 < Z) ? lrelu(a.z) : 0.0f;
                v.w = (rok && cc + 3 < Z) ? lrelu(a.w) : 0.0f;
                *(float4*)&s_z[lr][4 * cg] = v;
            }
        }
    }
    __syncthreads();

    // ---- P3: horizontal down-conv, 4 outputs/thread ----
    // group g: outputs 4g..4g+3 use z cols [8g, 8g+17]; read 5 float4s
    for (int e = tid; e < ZT * 8; e += 256) {
        int lr = e >> 3, g = e & 7;
        float4 W[5];
#pragma unroll
        for (int k = 0; k < 5; ++k)
            W[k] = *(const float4*)&s_z[lr][8 * g + 4 * k];
        float s0 = 0.f, s1 = 0.f, s2 = 0.f, s3 = 0.f;
#pragma unroll
        for (int t = 0; t < 12; ++t) {
            int i0 = 11 - t, i1 = 13 - t, i2 = 15 - t, i3 = 17 - t;
            s0 += fd[t] * f4c(W[i0 >> 2], i0 & 3);
            s1 += fd[t] * f4c(W[i1 >> 2], i1 & 3);
            s2 += fd[t] * f4c(W[i2 >> 2], i2 & 3);
            s3 += fd[t] * f4c(W[i3 >> 2], i3 & 3);
        }
        float4 a = {s0, s1, s2, s3};
        *(float4*)&s_t3[lr][4 * g] = a;
    }
    __syncthreads();

    // ---- P4: vertical down-conv + crop + store, 4 outputs/thread ----
    {
        int li = tid >> 3, g = tid & 7;     // exactly 256 elems
        float4 a = {0.f, 0.f, 0.f, 0.f};
#pragma unroll
        for (int s = 0; s < 12; ++s) {
            float4 Wv = *(const float4*)&s_t3[2 * li + 11 - s][4 * g];
            F4FMA(a, fd[s], Wv);
        }
        int i = oy0 + li, j = ox0 + 4 * g;
        if (i < OUT_HW && j < OUT_HW) {
            float* o = out + (size_t)pz * OUT_HW * OUT_HW;
            *(float4*)&o[(size_t)i * OUT_HW + j] = a;
        }
    }
}

extern "C" void kernel_launch(void* const* d_in, const int* in_sizes, int n_in,
                              void* d_out, int out_size, void* d_ws, size_t ws_size,
                              hipStream_t stream) {
    const float* x  = (const float*)d_in[0];
    const float* ku = (const float*)d_in[1];
    const float* kd = (const float*)d_in[2];
    float* out = (float*)d_out;

    const int planes = 2 * 256;
    const int tiles  = (OUT_HW + TILE - 1) / TILE;   // 5
    dim3 grid(tiles, tiles, planes);
    afa_fused<<<grid, dim3(256), 0, stream>>>(x, ku, kd, out);
}